// Round 6
// baseline (184.259 us; speedup 1.0000x reference)
//
#include <hip/hip_runtime.h>
#include <math.h>

// LinearAttention: out[n,l,h,m] = (phi(Q[l])·KV[:,m]) / (phi(Q[l])·Ksum + eps)
//   KV[d][m] = sum_s phi(K[s,d]) V[s,m],  Ksum[d] = sum_s phi(K[s,d])
//   phi(x) = elu(x)+1 = x>0 ? x+1 : exp(x)

#define N_B 8
#define S_LEN 8192
#define H_N 8
#define D_DIM 64
#define NH (N_B * H_N)
#define EPS 1e-6f
#define ROWSTRIDE (H_N * D_DIM)   // 512 floats between consecutive s rows
#define NCHUNK 16
#define TS 32                      // rows per LDS tile
#define TILES (S_LEN / NCHUNK / TS) // 16 tiles per block
#define KPAD 68                    // padded K-tile row stride

__device__ __forceinline__ float felu1(float x) {
    return x > 0.0f ? x + 1.0f : __expf(x);
}

__device__ __forceinline__ void gload_lds16(const float* g, float* lds_base) {
    __builtin_amdgcn_global_load_lds(
        (const __attribute__((address_space(1))) unsigned int*)g,
        (__attribute__((address_space(3))) unsigned int*)lds_base, 16, 0, 0);
}

// ---------------- Phase 1a: block per (nh, chunk) ----------------
// 4 waves x 8 rows each, 8x8 register tile per lane, double-buffered LDS.
// KEY: staging and compute are wave-local (wave w stages AND computes rows
// 8w..8w+7) -> NO per-tile __syncthreads. Per-wave ordering via explicit
// s_waitcnt vmcnt(N) (N = next tile's 4 in-flight loads) + compiler lgkmcnt.
__global__ __launch_bounds__(256) void kv_partial_kernel(
        const float* __restrict__ Kin, const float* __restrict__ Vin,
        float* __restrict__ kvp,   // [NH*NCHUNK][64*64]
        float* __restrict__ ksp) { // [NH*NCHUNK][64]
    __shared__ __align__(16) float Ks[2][TS][KPAD];  // 17.4 KB
    __shared__ __align__(16) float Vs[2][TS][D_DIM]; // 16.4 KB (linear)

    const int b  = blockIdx.x;
    const int nh = b / NCHUNK;
    const int c  = b - nh * NCHUNK;
    const int n_i = nh >> 3, h_i = nh & 7;
    const int s0  = c * (S_LEN / NCHUNK);

    const int t = threadIdx.x;
    const int w = t >> 6;        // wave 0..3
    const int l = t & 63;        // lane
    const int d8 = l >> 3;       // 0..7 -> d rows d8*8..+7
    const int m8 = l & 7;        // 0..7 -> m cols m8*8..+7

    const float* Kb = Kin + (size_t)n_i * S_LEN * ROWSTRIDE + (size_t)h_i * D_DIM;
    const float* Vb = Vin + (size_t)n_i * S_LEN * ROWSTRIDE + (size_t)h_i * D_DIM;

    float acc[8][8];
    #pragma unroll
    for (int i = 0; i < 8; ++i)
        #pragma unroll
        for (int j = 0; j < 8; ++j) acc[i][j] = 0.0f;
    float ksphi[8];
    #pragma unroll
    for (int i = 0; i < 8; ++i) ksphi[i] = 0.0f;

    // staging roles: thread t -> K row t>>3 (wave-local: rows 8w..8w+7)
    const int srow = t >> 3;
    const int scol = (t & 7) * 8;

    float4 kra, krb;   // in-flight K registers

    auto v_issue = [&](int buf, int tile) {
        const int sr = s0 + tile * TS;
        #pragma unroll
        for (int j = 0; j < 2; ++j) {
            const float* gp = Vb + (size_t)(sr + w * 8 + j * 4 + (l >> 4)) * ROWSTRIDE
                            + (l & 15) * 4;
            gload_lds16(gp, &Vs[buf][w * 8 + j * 4][0]);
        }
    };
    auto k_issue = [&](int tile) {
        const float* kp = Kb + (size_t)(s0 + tile * TS + srow) * ROWSTRIDE + scol;
        kra = *(const float4*)kp;
        krb = *(const float4*)(kp + 4);
    };
    auto k_write = [&](int buf) {
        float4 fa, fb;
        fa.x = felu1(kra.x); fa.y = felu1(kra.y);
        fa.z = felu1(kra.z); fa.w = felu1(kra.w);
        fb.x = felu1(krb.x); fb.y = felu1(krb.y);
        fb.z = felu1(krb.z); fb.w = felu1(krb.w);
        ksphi[0] += fa.x; ksphi[1] += fa.y; ksphi[2] += fa.z; ksphi[3] += fa.w;
        ksphi[4] += fb.x; ksphi[5] += fb.y; ksphi[6] += fb.z; ksphi[7] += fb.w;
        *(float4*)&Ks[buf][srow][scol]     = fa;
        *(float4*)&Ks[buf][srow][scol + 4] = fb;
    };

    // prologue: full stage of tile 0 (k_write's register use drains K loads)
    v_issue(0, 0);
    k_issue(0);
    k_write(0);

    int cur = 0;
    for (int tile = 0; tile < TILES; ++tile) {
        const bool more = (tile + 1 < TILES);
        if (more) {
            v_issue(cur ^ 1, tile + 1);   // async into LDS (this wave's rows)
            k_issue(tile + 1);            // async into regs
            // wait until only next tile's 4 loads outstanding -> this tile's
            // V is in LDS (in-order vmcnt retire)
            asm volatile("s_waitcnt vmcnt(4)" ::: "memory");
        } else {
            asm volatile("s_waitcnt vmcnt(0)" ::: "memory");
        }
        __builtin_amdgcn_sched_barrier(0);
        #pragma unroll
        for (int rr = 0; rr < 8; ++rr) {
            const int r = w * 8 + rr;
            const float4 k0 = *(const float4*)&Ks[cur][r][d8 * 8];
            const float4 k1 = *(const float4*)&Ks[cur][r][d8 * 8 + 4];
            const float4 v0 = *(const float4*)&Vs[cur][r][m8 * 8];
            const float4 v1 = *(const float4*)&Vs[cur][r][m8 * 8 + 4];
            acc[0][0] += k0.x*v0.x; acc[0][1] += k0.x*v0.y; acc[0][2] += k0.x*v0.z; acc[0][3] += k0.x*v0.w;
            acc[0][4] += k0.x*v1.x; acc[0][5] += k0.x*v1.y; acc[0][6] += k0.x*v1.z; acc[0][7] += k0.x*v1.w;
            acc[1][0] += k0.y*v0.x; acc[1][1] += k0.y*v0.y; acc[1][2] += k0.y*v0.z; acc[1][3] += k0.y*v0.w;
            acc[1][4] += k0.y*v1.x; acc[1][5] += k0.y*v1.y; acc[1][6] += k0.y*v1.z; acc[1][7] += k0.y*v1.w;
            acc[2][0] += k0.z*v0.x; acc[2][1] += k0.z*v0.y; acc[2][2] += k0.z*v0.z; acc[2][3] += k0.z*v0.w;
            acc[2][4] += k0.z*v1.x; acc[2][5] += k0.z*v1.y; acc[2][6] += k0.z*v1.z; acc[2][7] += k0.z*v1.w;
            acc[3][0] += k0.w*v0.x; acc[3][1] += k0.w*v0.y; acc[3][2] += k0.w*v0.z; acc[3][3] += k0.w*v0.w;
            acc[3][4] += k0.w*v1.x; acc[3][5] += k0.w*v1.y; acc[3][6] += k0.w*v1.z; acc[3][7] += k0.w*v1.w;
            acc[4][0] += k1.x*v0.x; acc[4][1] += k1.x*v0.y; acc[4][2] += k1.x*v0.z; acc[4][3] += k1.x*v0.w;
            acc[4][4] += k1.x*v1.x; acc[4][5] += k1.x*v1.y; acc[4][6] += k1.x*v1.z; acc[4][7] += k1.x*v1.w;
            acc[5][0] += k1.y*v0.x; acc[5][1] += k1.y*v0.y; acc[5][2] += k1.y*v0.z; acc[5][3] += k1.y*v0.w;
            acc[5][4] += k1.y*v1.x; acc[5][5] += k1.y*v1.y; acc[5][6] += k1.y*v1.z; acc[5][7] += k1.y*v1.w;
            acc[6][0] += k1.z*v0.x; acc[6][1] += k1.z*v0.y; acc[6][2] += k1.z*v0.z; acc[6][3] += k1.z*v0.w;
            acc[6][4] += k1.z*v1.x; acc[6][5] += k1.z*v1.y; acc[6][6] += k1.z*v1.z; acc[6][7] += k1.z*v1.w;
            acc[7][0] += k1.w*v0.x; acc[7][1] += k1.w*v0.y; acc[7][2] += k1.w*v0.z; acc[7][3] += k1.w*v0.w;
            acc[7][4] += k1.w*v1.x; acc[7][5] += k1.w*v1.y; acc[7][6] += k1.w*v1.z; acc[7][7] += k1.w*v1.w;
        }
        __builtin_amdgcn_sched_barrier(0);
        if (more) k_write(cur ^ 1);   // phi + ds_write of next tile's K
        cur ^= 1;
    }

    // ---- cross-wave merge in LDS (needs barriers; 4 total, negligible) ----
    float* L0  = &Ks[0][0][0];
    float* L1  = &Vs[0][0][0];
    float* KSL = L1;

    __syncthreads();   // all waves done with free-running loop
    if (w == 1 || w == 3) {
        float* L = (w == 1) ? L0 : L1;
        #pragma unroll
        for (int i = 0; i < 8; ++i) {
            float* p = L + (d8 * 8 + i) * 64 + m8 * 8;
            *(float4*)p       = make_float4(acc[i][0], acc[i][1], acc[i][2], acc[i][3]);
            *(float4*)(p + 4) = make_float4(acc[i][4], acc[i][5], acc[i][6], acc[i][7]);
        }
    }
    __syncthreads();
    if (w == 0 || w == 2) {
        const float* L = (w == 0) ? L0 : L1;
        #pragma unroll
        for (int i = 0; i < 8; ++i) {
            const float* p = L + (d8 * 8 + i) * 64 + m8 * 8;
            const float4 x = *(const float4*)p;
            const float4 y = *(const float4*)(p + 4);
            acc[i][0] += x.x; acc[i][1] += x.y; acc[i][2] += x.z; acc[i][3] += x.w;
            acc[i][4] += y.x; acc[i][5] += y.y; acc[i][6] += y.z; acc[i][7] += y.w;
        }
    }
    __syncthreads();
    if (w == 2) {
        #pragma unroll
        for (int i = 0; i < 8; ++i) {
            float* p = L0 + (d8 * 8 + i) * 64 + m8 * 8;
            *(float4*)p       = make_float4(acc[i][0], acc[i][1], acc[i][2], acc[i][3]);
            *(float4*)(p + 4) = make_float4(acc[i][4], acc[i][5], acc[i][6], acc[i][7]);
        }
    }
    {
        float* p = KSL + srow * 64 + scol;
        *(float4*)p       = make_float4(ksphi[0], ksphi[1], ksphi[2], ksphi[3]);
        *(float4*)(p + 4) = make_float4(ksphi[4], ksphi[5], ksphi[6], ksphi[7]);
    }
    __syncthreads();
    if (w == 0) {
        float* kvo = kvp + (size_t)b * (D_DIM * D_DIM);
        #pragma unroll
        for (int i = 0; i < 8; ++i) {
            const float* p = L0 + (d8 * 8 + i) * 64 + m8 * 8;
            const float4 x = *(const float4*)p;
            const float4 y = *(const float4*)(p + 4);
            float4 o1, o2;
            o1.x = acc[i][0] + x.x; o1.y = acc[i][1] + x.y;
            o1.z = acc[i][2] + x.z; o1.w = acc[i][3] + x.w;
            o2.x = acc[i][4] + y.x; o2.y = acc[i][5] + y.y;
            o2.z = acc[i][6] + y.z; o2.w = acc[i][7] + y.w;
            float* q = kvo + (d8 * 8 + i) * 64 + m8 * 8;
            *(float4*)q       = o1;
            *(float4*)(q + 4) = o2;
        }
    }
    if (t < D_DIM) {
        float s = 0.0f;
        #pragma unroll
        for (int r = 0; r < 32; ++r) s += KSL[r * 64 + t];
        ksp[(size_t)b * D_DIM + t] = s;
    }
}

// ---------------- Phase 1b: reduce partials -> final KV, Ksum ----------------
__global__ __launch_bounds__(256) void kv_reduce_kernel(
        const float* __restrict__ kvp, const float* __restrict__ ksp,
        float* __restrict__ KV, float* __restrict__ Ksum) {
    const int nh = blockIdx.x >> 4;
    const int eb = blockIdx.x & 15;
    const int t  = threadIdx.x;
    const int e  = eb * 256 + t;
    float s = 0.0f;
    const float* base = kvp + (size_t)nh * NCHUNK * (D_DIM * D_DIM) + e;
    #pragma unroll
    for (int c = 0; c < NCHUNK; ++c)
        s += base[(size_t)c * (D_DIM * D_DIM)];
    KV[(size_t)nh * (D_DIM * D_DIM) + e] = s;
    if (eb == 0 && t < D_DIM) {
        float ks = 0.0f;
        const float* kb = ksp + (size_t)nh * NCHUNK * D_DIM + t;
        #pragma unroll
        for (int c = 0; c < NCHUNK; ++c) ks += kb[(size_t)c * D_DIM];
        Ksum[(size_t)nh * D_DIM + t] = ks;
    }
}

// ---------------- Phase 2: out = (Q·KV) / (Q·Ksum + eps) ----------------
__global__ __launch_bounds__(256) void out_kernel(
        const float* __restrict__ Qin, const float* __restrict__ KV,
        const float* __restrict__ Ksum, float* __restrict__ Out) {
    constexpr int RPB  = 128;
    constexpr int QPAD = 68;
    __shared__ __align__(16) float KVs[D_DIM][D_DIM];   // 16 KB
    __shared__ __align__(16) float Kss[D_DIM];
    __shared__ __align__(16) float Qs[RPB][QPAD];       // 34.8 KB, XOR-swizzled cols

    const int b    = blockIdx.x;
    const int nblk = S_LEN / RPB;          // 64
    const int nh   = b / nblk;
    const int rb   = b - nh * nblk;
    const int n_i  = nh >> 3, h_i = nh & 7;
    const int t    = threadIdx.x;

    const float* Qb = Qin + (size_t)n_i * S_LEN * ROWSTRIDE + (size_t)h_i * D_DIM;
    float*       Ob = Out + (size_t)n_i * S_LEN * ROWSTRIDE + (size_t)h_i * D_DIM;

    {
        const float4* src = (const float4*)(KV + (size_t)nh * (D_DIM * D_DIM));
        float4* dst = (float4*)(&KVs[0][0]);
        #pragma unroll
        for (int i = 0; i < 4; ++i) dst[t + 256 * i] = src[t + 256 * i];
        if (t < 16) ((float4*)Kss)[t] = ((const float4*)(Ksum + (size_t)nh * D_DIM))[t];
    }

    const int ltx = t & 15, lty = t >> 4;
    const int sbase = rb * RPB;
    #pragma unroll
    for (int i = 0; i < 8; ++i) {
        const int row = lty + 16 * i;
        const float4 q = *(const float4*)(Qb + (size_t)(sbase + row) * ROWSTRIDE + ltx * 4);
        float4 f;
        f.x = felu1(q.x); f.y = felu1(q.y); f.z = felu1(q.z); f.w = felu1(q.w);
        const int pc = (ltx * 4) ^ (((row >> 2) & 7) << 2);
        *(float4*)&Qs[row][pc] = f;
    }
    __syncthreads();

    const int rg = t >> 3;                 // 0..31 -> rows rg*4..rg*4+3
    const int mg = t & 7;                  // 0..7  -> cols mg*8..mg*8+7
    const int r0 = rg * 4, m0 = mg * 8;
    const int sw = ((rg & 7) << 2);

    float acc[4][8];
    float zz[4];
    #pragma unroll
    for (int r = 0; r < 4; ++r) {
        zz[r] = 0.0f;
        #pragma unroll
        for (int m = 0; m < 8; ++m) acc[r][m] = 0.0f;
    }

    #pragma unroll
    for (int d0 = 0; d0 < D_DIM; d0 += 4) {
        const float4 ks4 = *(const float4*)&Kss[d0];
        float4 qr[4];
        #pragma unroll
        for (int r = 0; r < 4; ++r) {
            qr[r] = *(const float4*)&Qs[r0 + r][d0 ^ sw];
            zz[r] += qr[r].x * ks4.x + qr[r].y * ks4.y
                   + qr[r].z * ks4.z + qr[r].w * ks4.w;
        }
        #pragma unroll
        for (int j = 0; j < 4; ++j) {
            const float4 kva = *(const float4*)&KVs[d0 + j][m0];
            const float4 kvb = *(const float4*)&KVs[d0 + j][m0 + 4];
            #pragma unroll
            for (int r = 0; r < 4; ++r) {
                const float q = (&qr[r].x)[j];
                acc[r][0] += q * kva.x; acc[r][1] += q * kva.y;
                acc[r][2] += q * kva.z; acc[r][3] += q * kva.w;
                acc[r][4] += q * kvb.x; acc[r][5] += q * kvb.y;
                acc[r][6] += q * kvb.z; acc[r][7] += q * kvb.w;
            }
        }
    }

    #pragma unroll
    for (int r = 0; r < 4; ++r) {
        const float z = 1.0f / (zz[r] + EPS);
        float4 o1, o2;
        o1.x = acc[r][0] * z; o1.y = acc[r][1] * z;
        o1.z = acc[r][2] * z; o1.w = acc[r][3] * z;
        o2.x = acc[r][4] * z; o2.y = acc[r][5] * z;
        o2.z = acc[r][6] * z; o2.w = acc[r][7] * z;
        float* op = Ob + (size_t)(sbase + r0 + r) * ROWSTRIDE + m0;
        *(float4*)op       = o1;
        *(float4*)(op + 4) = o2;
    }
}

extern "C" void kernel_launch(void* const* d_in, const int* in_sizes, int n_in,
                              void* d_out, int out_size, void* d_ws, size_t ws_size,
                              hipStream_t stream) {
    const float* q = (const float*)d_in[0];
    const float* k = (const float*)d_in[1];
    const float* v = (const float*)d_in[2];
    float* out = (float*)d_out;

    float* kvp  = (float*)d_ws;
    float* ksp  = kvp + (size_t)NH * NCHUNK * D_DIM * D_DIM;
    float* KVf  = ksp + (size_t)NH * NCHUNK * D_DIM;
    float* Ksum = KVf + (size_t)NH * D_DIM * D_DIM;

    kv_partial_kernel<<<NH * NCHUNK, 256, 0, stream>>>(k, v, kvp, ksp);
    kv_reduce_kernel<<<NH * 16, 256, 0, stream>>>(kvp, ksp, KVf, Ksum);
    out_kernel<<<NH * (S_LEN / 128), 256, 0, stream>>>(q, KVf, Ksum, out);
}

// Round 7
// 166.108 us; speedup vs baseline: 1.1093x; 1.1093x over previous
//
#include <hip/hip_runtime.h>
#include <math.h>

// LinearAttention: out[n,l,h,m] = (phi(Q[l])·KV[:,m]) / (phi(Q[l])·Ksum + eps)
//   KV[d][m] = sum_s phi(K[s,d]) V[s,m],  Ksum[d] = sum_s phi(K[s,d])
//   phi(x) = elu(x)+1 = x>0 ? x+1 : exp(x)

#define N_B 8
#define S_LEN 8192
#define H_N 8
#define D_DIM 64
#define NH (N_B * H_N)
#define EPS 1e-6f
#define ROWSTRIDE (H_N * D_DIM)   // 512 floats between consecutive s rows
#define NCHUNK 16
#define TS 32                      // rows per LDS tile
#define TILES (S_LEN / NCHUNK / TS) // 16 tiles per block

typedef __attribute__((ext_vector_type(8)))  __bf16 bf16x8;
typedef __attribute__((ext_vector_type(4)))  float  f32x4;
typedef __attribute__((ext_vector_type(4)))  int    i32x4;

__device__ __forceinline__ float felu1(float x) {
    return x > 0.0f ? x + 1.0f : __expf(x);
}

// ---------------- Phase 1a: MFMA KV partial, block per (nh, chunk) ----------
// KV = phi(K)^T V via mfma_f32_16x16x32_bf16 with hi/lo bf16 split (fp32-
// accurate: hi*hi + hi*lo + lo*hi, lo*lo ~2^-16 dropped).
// LDS: KT[d][s], VT[m][s] transposed tiles, interleaved hi|lo in 128B rows of
// 8x16B groups, phys_group = logical ^ (row&7) (bijective, conflict-free).
// Staging: column-gather global loads (coalesced 256B/row), convert AFTER the
// compute phase (T14). Wave w owns output rows d in [16w,16w+16) -> no merge.
__global__ __launch_bounds__(256) void kv_partial_kernel(
        const float* __restrict__ Kin, const float* __restrict__ Vin,
        float* __restrict__ kvp,   // [NH*NCHUNK][64*64]
        float* __restrict__ ksp) { // [NH*NCHUNK][64]
    __shared__ __align__(16) unsigned int KT[2][64 * 32]; // 8 KB per buffer
    __shared__ __align__(16) unsigned int VT[2][64 * 32]; // 8 KB per buffer

    const int b  = blockIdx.x;
    const int nh = b / NCHUNK;
    const int c  = b - nh * NCHUNK;
    const int n_i = nh >> 3, h_i = nh & 7;
    const int s0  = c * (S_LEN / NCHUNK);

    const int t = threadIdx.x;
    const int w = t >> 6;        // wave 0..3
    const int l = t & 63;        // lane
    const int d = l;             // staging column (d for K, m for V)

    const float* Kb = Kin + (size_t)n_i * S_LEN * ROWSTRIDE + (size_t)h_i * D_DIM;
    const float* Vb = Vin + (size_t)n_i * S_LEN * ROWSTRIDE + (size_t)h_i * D_DIM;

    float kraw[8], vraw[8];      // in-flight column gathers (8 s-rows, 1 col)
    float ksum = 0.0f;

    auto issue = [&](int tile) {
        const int sr = s0 + tile * TS + w * 8;
        #pragma unroll
        for (int e = 0; e < 8; ++e) {
            kraw[e] = Kb[(size_t)(sr + e) * ROWSTRIDE + d];
            vraw[e] = Vb[(size_t)(sr + e) * ROWSTRIDE + d];
        }
    };

    // phi (K only), hi/lo truncation split, pack pairs, swizzled LDS write
    auto convert_write = [&](int buf) {
        unsigned int kh[4], kl[4], vh[4], vl[4];
        #pragma unroll
        for (int p = 0; p < 4; ++p) {
            const float x0 = felu1(kraw[2 * p]);
            const float x1 = felu1(kraw[2 * p + 1]);
            ksum += x0 + x1;
            const unsigned u0 = __float_as_uint(x0), u1 = __float_as_uint(x1);
            const unsigned h0 = u0 & 0xFFFF0000u,    h1 = u1 & 0xFFFF0000u;
            const float r0 = x0 - __uint_as_float(h0);
            const float r1 = x1 - __uint_as_float(h1);
            kh[p] = (h0 >> 16) | h1;
            kl[p] = (__float_as_uint(r0) >> 16) | (__float_as_uint(r1) & 0xFFFF0000u);
            const float y0 = vraw[2 * p], y1 = vraw[2 * p + 1];
            const unsigned q0 = __float_as_uint(y0), q1 = __float_as_uint(y1);
            const unsigned g0 = q0 & 0xFFFF0000u,    g1 = q1 & 0xFFFF0000u;
            const float z0 = y0 - __uint_as_float(g0);
            const float z1 = y1 - __uint_as_float(g1);
            vh[p] = (g0 >> 16) | g1;
            vl[p] = (__float_as_uint(z0) >> 16) | (__float_as_uint(z1) & 0xFFFF0000u);
        }
        const int ph = ((w)     ^ (d & 7)) * 4;   // hi group (logical w)
        const int pl = ((w + 4) ^ (d & 7)) * 4;   // lo group (logical 4+w)
        unsigned int* kr = &KT[buf][d * 32];
        unsigned int* vr = &VT[buf][d * 32];
        *(i32x4*)&kr[ph] = (i32x4){(int)kh[0], (int)kh[1], (int)kh[2], (int)kh[3]};
        *(i32x4*)&kr[pl] = (i32x4){(int)kl[0], (int)kl[1], (int)kl[2], (int)kl[3]};
        *(i32x4*)&vr[ph] = (i32x4){(int)vh[0], (int)vh[1], (int)vh[2], (int)vh[3]};
        *(i32x4*)&vr[pl] = (i32x4){(int)vl[0], (int)vl[1], (int)vl[2], (int)vl[3]};
    };

    f32x4 acc0 = {0.f, 0.f, 0.f, 0.f};
    f32x4 acc1 = {0.f, 0.f, 0.f, 0.f};
    f32x4 acc2 = {0.f, 0.f, 0.f, 0.f};
    f32x4 acc3 = {0.f, 0.f, 0.f, 0.f};

    // fragment read offsets (dword units): row*32 + physgroup*4
    const int arow = 16 * w + (l & 15);                 // A row = d (wave slab)
    const int ghi  = ((l >> 4) ^ (l & 7));              // phys hi group
    const int glo  = ((4 + (l >> 4)) ^ (l & 7));        // phys lo group
    const int aoff_h = arow * 32 + ghi * 4;
    const int aoff_l = arow * 32 + glo * 4;
    const int brow0  = (l & 15) * 32;                   // B row = m-tile base

    issue(0);
    convert_write(0);
    __syncthreads();

    int cur = 0;
    for (int tile = 0; tile < TILES; ++tile) {
        const bool more = (tile + 1 < TILES);
        if (more) issue(tile + 1);

        const bf16x8 Ahi = __builtin_bit_cast(bf16x8, *(const i32x4*)&KT[cur][aoff_h]);
        const bf16x8 Alo = __builtin_bit_cast(bf16x8, *(const i32x4*)&KT[cur][aoff_l]);
        #pragma unroll
        for (int mt = 0; mt < 4; ++mt) {
            const int bo = brow0 + mt * 16 * 32;
            const bf16x8 Bhi = __builtin_bit_cast(bf16x8, *(const i32x4*)&VT[cur][bo + ghi * 4]);
            const bf16x8 Blo = __builtin_bit_cast(bf16x8, *(const i32x4*)&VT[cur][bo + glo * 4]);
            f32x4* acc = (mt == 0) ? &acc0 : (mt == 1) ? &acc1 : (mt == 2) ? &acc2 : &acc3;
            *acc = __builtin_amdgcn_mfma_f32_16x16x32_bf16(Ahi, Bhi, *acc, 0, 0, 0);
            *acc = __builtin_amdgcn_mfma_f32_16x16x32_bf16(Ahi, Blo, *acc, 0, 0, 0);
            *acc = __builtin_amdgcn_mfma_f32_16x16x32_bf16(Alo, Bhi, *acc, 0, 0, 0);
        }

        if (more) convert_write(cur ^ 1);   // vmcnt wait lands here (T14)
        __syncthreads();
        cur ^= 1;
    }

    // ---- write partials: D[row][col], col = l&15, row = (l>>4)*4 + reg ----
    float* kvo = kvp + (size_t)b * (D_DIM * D_DIM);
    #pragma unroll
    for (int mt = 0; mt < 4; ++mt) {
        const f32x4 a = (mt == 0) ? acc0 : (mt == 1) ? acc1 : (mt == 2) ? acc2 : acc3;
        #pragma unroll
        for (int r = 0; r < 4; ++r) {
            const int row = 16 * w + (l >> 4) * 4 + r;   // d
            const int col = 16 * mt + (l & 15);          // m
            kvo[row * 64 + col] = a[r];
        }
    }

    // ---- ksum: per-thread column partial -> LDS reduce over 4 waves ----
    float* ksl = (float*)&KT[0][0];
    __syncthreads();
    ksl[w * 64 + d] = ksum;
    __syncthreads();
    if (t < D_DIM) {
        ksp[(size_t)b * D_DIM + t] =
            ksl[t] + ksl[64 + t] + ksl[128 + t] + ksl[192 + t];
    }
}

// ---------------- Phase 1b: reduce partials -> final KV, Ksum ----------------
__global__ __launch_bounds__(256) void kv_reduce_kernel(
        const float* __restrict__ kvp, const float* __restrict__ ksp,
        float* __restrict__ KV, float* __restrict__ Ksum) {
    const int nh = blockIdx.x >> 4;
    const int eb = blockIdx.x & 15;
    const int t  = threadIdx.x;
    const int e  = eb * 256 + t;
    float s = 0.0f;
    const float* base = kvp + (size_t)nh * NCHUNK * (D_DIM * D_DIM) + e;
    #pragma unroll
    for (int c = 0; c < NCHUNK; ++c)
        s += base[(size_t)c * (D_DIM * D_DIM)];
    KV[(size_t)nh * (D_DIM * D_DIM) + e] = s;
    if (eb == 0 && t < D_DIM) {
        float ks = 0.0f;
        const float* kb = ksp + (size_t)nh * NCHUNK * D_DIM + t;
        #pragma unroll
        for (int c = 0; c < NCHUNK; ++c) ks += kb[(size_t)c * D_DIM];
        Ksum[(size_t)nh * D_DIM + t] = ks;
    }
}

// ---------------- Phase 2: out = (Q·KV) / (Q·Ksum + eps) ----------------
__global__ __launch_bounds__(256) void out_kernel(
        const float* __restrict__ Qin, const float* __restrict__ KV,
        const float* __restrict__ Ksum, float* __restrict__ Out) {
    constexpr int RPB  = 128;
    constexpr int QPAD = 68;
    __shared__ __align__(16) float KVs[D_DIM][D_DIM];   // 16 KB
    __shared__ __align__(16) float Kss[D_DIM];
    __shared__ __align__(16) float Qs[RPB][QPAD];       // 34.8 KB, XOR-swizzled cols

    const int b    = blockIdx.x;
    const int nblk = S_LEN / RPB;          // 64
    const int nh   = b / nblk;
    const int rb   = b - nh * nblk;
    const int n_i  = nh >> 3, h_i = nh & 7;
    const int t    = threadIdx.x;

    const float* Qb = Qin + (size_t)n_i * S_LEN * ROWSTRIDE + (size_t)h_i * D_DIM;
    float*       Ob = Out + (size_t)n_i * S_LEN * ROWSTRIDE + (size_t)h_i * D_DIM;

    {
        const float4* src = (const float4*)(KV + (size_t)nh * (D_DIM * D_DIM));
        float4* dst = (float4*)(&KVs[0][0]);
        #pragma unroll
        for (int i = 0; i < 4; ++i) dst[t + 256 * i] = src[t + 256 * i];
        if (t < 16) ((float4*)Kss)[t] = ((const float4*)(Ksum + (size_t)nh * D_DIM))[t];
    }

    const int ltx = t & 15, lty = t >> 4;
    const int sbase = rb * RPB;
    #pragma unroll
    for (int i = 0; i < 8; ++i) {
        const int row = lty + 16 * i;
        const float4 q = *(const float4*)(Qb + (size_t)(sbase + row) * ROWSTRIDE + ltx * 4);
        float4 f;
        f.x = felu1(q.x); f.y = felu1(q.y); f.z = felu1(q.z); f.w = felu1(q.w);
        const int pc = (ltx * 4) ^ (((row >> 2) & 7) << 2);
        *(float4*)&Qs[row][pc] = f;
    }
    __syncthreads();

    const int rg = t >> 3;                 // 0..31 -> rows rg*4..rg*4+3
    const int mg = t & 7;                  // 0..7  -> cols mg*8..mg*8+7
    const int r0 = rg * 4, m0 = mg * 8;
    const int sw = ((rg & 7) << 2);

    float acc[4][8];
    float zz[4];
    #pragma unroll
    for (int r = 0; r < 4; ++r) {
        zz[r] = 0.0f;
        #pragma unroll
        for (int m = 0; m < 8; ++m) acc[r][m] = 0.0f;
    }

    #pragma unroll
    for (int d0 = 0; d0 < D_DIM; d0 += 4) {
        const float4 ks4 = *(const float4*)&Kss[d0];
        float4 qr[4];
        #pragma unroll
        for (int r = 0; r < 4; ++r) {
            qr[r] = *(const float4*)&Qs[r0 + r][d0 ^ sw];
            zz[r] += qr[r].x * ks4.x + qr[r].y * ks4.y
                   + qr[r].z * ks4.z + qr[r].w * ks4.w;
        }
        #pragma unroll
        for (int j = 0; j < 4; ++j) {
            const float4 kva = *(const float4*)&KVs[d0 + j][m0];
            const float4 kvb = *(const float4*)&KVs[d0 + j][m0 + 4];
            #pragma unroll
            for (int r = 0; r < 4; ++r) {
                const float q = (&qr[r].x)[j];
                acc[r][0] += q * kva.x; acc[r][1] += q * kva.y;
                acc[r][2] += q * kva.z; acc[r][3] += q * kva.w;
                acc[r][4] += q * kvb.x; acc[r][5] += q * kvb.y;
                acc[r][6] += q * kvb.z; acc[r][7] += q * kvb.w;
            }
        }
    }

    #pragma unroll
    for (int r = 0; r < 4; ++r) {
        const float z = 1.0f / (zz[r] + EPS);
        float4 o1, o2;
        o1.x = acc[r][0] * z; o1.y = acc[r][1] * z;
        o1.z = acc[r][2] * z; o1.w = acc[r][3] * z;
        o2.x = acc[r][4] * z; o2.y = acc[r][5] * z;
        o2.z = acc[r][6] * z; o2.w = acc[r][7] * z;
        float* op = Ob + (size_t)(sbase + r0 + r) * ROWSTRIDE + m0;
        *(float4*)op       = o1;
        *(float4*)(op + 4) = o2;
    }
}

extern "C" void kernel_launch(void* const* d_in, const int* in_sizes, int n_in,
                              void* d_out, int out_size, void* d_ws, size_t ws_size,
                              hipStream_t stream) {
    const float* q = (const float*)d_in[0];
    const float* k = (const float*)d_in[1];
    const float* v = (const float*)d_in[2];
    float* out = (float*)d_out;

    float* kvp  = (float*)d_ws;
    float* ksp  = kvp + (size_t)NH * NCHUNK * D_DIM * D_DIM;
    float* KVf  = ksp + (size_t)NH * NCHUNK * D_DIM;
    float* Ksum = KVf + (size_t)NH * D_DIM * D_DIM;

    kv_partial_kernel<<<NH * NCHUNK, 256, 0, stream>>>(k, v, kvp, ksp);
    kv_reduce_kernel<<<NH * 16, 256, 0, stream>>>(kvp, ksp, KVf, Ksum);
    out_kernel<<<NH * (S_LEN / 128), 256, 0, stream>>>(q, KVf, Ksum, out);
}

// Round 8
// 155.443 us; speedup vs baseline: 1.1854x; 1.0686x over previous
//
#include <hip/hip_runtime.h>
#include <math.h>

// LinearAttention: out[n,l,h,m] = (phi(Q[l])·KV[:,m]) / (phi(Q[l])·Ksum + eps)
//   KV[d][m] = sum_s phi(K[s,d]) V[s,m],  Ksum[d] = sum_s phi(K[s,d])
//   phi(x) = elu(x)+1 = x>0 ? x+1 : exp(x)

#define N_B 8
#define S_LEN 8192
#define H_N 8
#define D_DIM 64
#define NH (N_B * H_N)
#define EPS 1e-6f
#define ROWSTRIDE (H_N * D_DIM)   // 512 floats between consecutive s rows
#define NCHUNK 16
#define TS 32                      // rows per LDS tile
#define TILES (S_LEN / NCHUNK / TS) // 16 tiles per block

typedef __attribute__((ext_vector_type(8)))  __bf16 bf16x8;
typedef __attribute__((ext_vector_type(4)))  float  f32x4;
typedef __attribute__((ext_vector_type(4)))  int    i32x4;

__device__ __forceinline__ float felu1(float x) {
    return x > 0.0f ? x + 1.0f : __expf(x);
}

// ---------------- Phase 1a: MFMA KV partial ----------
// Grid remap: b = ((n*NCHUNK + c) * 8) + h  -> the 8 blocks covering all
// heads of the same (n, s-range) are consecutive, dispatched together, and
// stream the SAME contiguous rows in lockstep (DRAM page-friendly).
// KV = phi(K)^T V via mfma_f32_16x16x32_bf16 with hi/lo bf16 split.
__global__ __launch_bounds__(256) void kv_partial_kernel(
        const float* __restrict__ Kin, const float* __restrict__ Vin,
        float* __restrict__ kvp,   // [NH*NCHUNK][64*64]  (logical (nh,c) layout)
        float* __restrict__ ksp) { // [NH*NCHUNK][64]
    __shared__ __align__(16) unsigned int KT[2][64 * 32]; // 8 KB per buffer
    __shared__ __align__(16) unsigned int VT[2][64 * 32]; // 8 KB per buffer

    const int b    = blockIdx.x;
    const int h_i  = b & 7;
    const int rest = b >> 3;
    const int c    = rest & (NCHUNK - 1);
    const int n_i  = rest >> 4;                 // NCHUNK = 16
    const int nh   = n_i * H_N + h_i;
    const int ob   = nh * NCHUNK + c;           // logical partial index
    const int s0   = c * (S_LEN / NCHUNK);

    const int t = threadIdx.x;
    const int w = t >> 6;        // wave 0..3
    const int l = t & 63;        // lane
    const int d = l;             // staging column (d for K, m for V)

    const float* Kb = Kin + (size_t)n_i * S_LEN * ROWSTRIDE + (size_t)h_i * D_DIM;
    const float* Vb = Vin + (size_t)n_i * S_LEN * ROWSTRIDE + (size_t)h_i * D_DIM;

    float kraw[8], vraw[8];      // in-flight column gathers (8 s-rows, 1 col)
    float ksum = 0.0f;

    auto issue = [&](int tile) {
        const int sr = s0 + tile * TS + w * 8;
        #pragma unroll
        for (int e = 0; e < 8; ++e) {
            kraw[e] = Kb[(size_t)(sr + e) * ROWSTRIDE + d];
            vraw[e] = Vb[(size_t)(sr + e) * ROWSTRIDE + d];
        }
    };

    // phi (K only), hi/lo truncation split, pack pairs, swizzled LDS write
    auto convert_write = [&](int buf) {
        unsigned int kh[4], kl[4], vh[4], vl[4];
        #pragma unroll
        for (int p = 0; p < 4; ++p) {
            const float x0 = felu1(kraw[2 * p]);
            const float x1 = felu1(kraw[2 * p + 1]);
            ksum += x0 + x1;
            const unsigned u0 = __float_as_uint(x0), u1 = __float_as_uint(x1);
            const unsigned h0 = u0 & 0xFFFF0000u,    h1 = u1 & 0xFFFF0000u;
            const float r0 = x0 - __uint_as_float(h0);
            const float r1 = x1 - __uint_as_float(h1);
            kh[p] = (h0 >> 16) | h1;
            kl[p] = (__float_as_uint(r0) >> 16) | (__float_as_uint(r1) & 0xFFFF0000u);
            const float y0 = vraw[2 * p], y1 = vraw[2 * p + 1];
            const unsigned q0 = __float_as_uint(y0), q1 = __float_as_uint(y1);
            const unsigned g0 = q0 & 0xFFFF0000u,    g1 = q1 & 0xFFFF0000u;
            const float z0 = y0 - __uint_as_float(g0);
            const float z1 = y1 - __uint_as_float(g1);
            vh[p] = (g0 >> 16) | g1;
            vl[p] = (__float_as_uint(z0) >> 16) | (__float_as_uint(z1) & 0xFFFF0000u);
        }
        const int ph = ((w)     ^ (d & 7)) * 4;   // hi group (logical w)
        const int pl = ((w + 4) ^ (d & 7)) * 4;   // lo group (logical 4+w)
        unsigned int* kr = &KT[buf][d * 32];
        unsigned int* vr = &VT[buf][d * 32];
        *(i32x4*)&kr[ph] = (i32x4){(int)kh[0], (int)kh[1], (int)kh[2], (int)kh[3]};
        *(i32x4*)&kr[pl] = (i32x4){(int)kl[0], (int)kl[1], (int)kl[2], (int)kl[3]};
        *(i32x4*)&vr[ph] = (i32x4){(int)vh[0], (int)vh[1], (int)vh[2], (int)vh[3]};
        *(i32x4*)&vr[pl] = (i32x4){(int)vl[0], (int)vl[1], (int)vl[2], (int)vl[3]};
    };

    f32x4 acc0 = {0.f, 0.f, 0.f, 0.f};
    f32x4 acc1 = {0.f, 0.f, 0.f, 0.f};
    f32x4 acc2 = {0.f, 0.f, 0.f, 0.f};
    f32x4 acc3 = {0.f, 0.f, 0.f, 0.f};

    // fragment read offsets (dword units): row*32 + physgroup*4
    const int arow = 16 * w + (l & 15);                 // A row = d (wave slab)
    const int ghi  = ((l >> 4) ^ (l & 7));              // phys hi group
    const int glo  = ((4 + (l >> 4)) ^ (l & 7));        // phys lo group
    const int aoff_h = arow * 32 + ghi * 4;
    const int aoff_l = arow * 32 + glo * 4;
    const int brow0  = (l & 15) * 32;                   // B row = m-tile base

    issue(0);
    convert_write(0);
    __syncthreads();

    int cur = 0;
    for (int tile = 0; tile < TILES; ++tile) {
        const bool more = (tile + 1 < TILES);
        if (more) issue(tile + 1);

        const bf16x8 Ahi = __builtin_bit_cast(bf16x8, *(const i32x4*)&KT[cur][aoff_h]);
        const bf16x8 Alo = __builtin_bit_cast(bf16x8, *(const i32x4*)&KT[cur][aoff_l]);
        #pragma unroll
        for (int mt = 0; mt < 4; ++mt) {
            const int bo = brow0 + mt * 16 * 32;
            const bf16x8 Bhi = __builtin_bit_cast(bf16x8, *(const i32x4*)&VT[cur][bo + ghi * 4]);
            const bf16x8 Blo = __builtin_bit_cast(bf16x8, *(const i32x4*)&VT[cur][bo + glo * 4]);
            f32x4* acc = (mt == 0) ? &acc0 : (mt == 1) ? &acc1 : (mt == 2) ? &acc2 : &acc3;
            *acc = __builtin_amdgcn_mfma_f32_16x16x32_bf16(Ahi, Bhi, *acc, 0, 0, 0);
            *acc = __builtin_amdgcn_mfma_f32_16x16x32_bf16(Ahi, Blo, *acc, 0, 0, 0);
            *acc = __builtin_amdgcn_mfma_f32_16x16x32_bf16(Alo, Bhi, *acc, 0, 0, 0);
        }

        if (more) convert_write(cur ^ 1);   // vmcnt wait lands here (T14)
        __syncthreads();
        cur ^= 1;
    }

    // ---- write partials: D[row][col], col = l&15, row = (l>>4)*4 + reg ----
    float* kvo = kvp + (size_t)ob * (D_DIM * D_DIM);
    #pragma unroll
    for (int mt = 0; mt < 4; ++mt) {
        const f32x4 a = (mt == 0) ? acc0 : (mt == 1) ? acc1 : (mt == 2) ? acc2 : acc3;
        #pragma unroll
        for (int r = 0; r < 4; ++r) {
            const int row = 16 * w + (l >> 4) * 4 + r;   // d
            const int col = 16 * mt + (l & 15);          // m
            kvo[row * 64 + col] = a[r];
        }
    }

    // ---- ksum: per-thread column partial -> LDS reduce over 4 waves ----
    float* ksl = (float*)&KT[0][0];
    __syncthreads();
    ksl[w * 64 + d] = ksum;
    __syncthreads();
    if (t < D_DIM) {
        ksp[(size_t)ob * D_DIM + t] =
            ksl[t] + ksl[64 + t] + ksl[128 + t] + ksl[192 + t];
    }
}

// ---------------- Phase 1b: reduce partials -> final KV, Ksum ----------------
__global__ __launch_bounds__(256) void kv_reduce_kernel(
        const float* __restrict__ kvp, const float* __restrict__ ksp,
        float* __restrict__ KV, float* __restrict__ Ksum) {
    const int nh = blockIdx.x >> 4;
    const int eb = blockIdx.x & 15;
    const int t  = threadIdx.x;
    const int e  = eb * 256 + t;
    float s = 0.0f;
    const float* base = kvp + (size_t)nh * NCHUNK * (D_DIM * D_DIM) + e;
    #pragma unroll
    for (int c = 0; c < NCHUNK; ++c)
        s += base[(size_t)c * (D_DIM * D_DIM)];
    KV[(size_t)nh * (D_DIM * D_DIM) + e] = s;
    if (eb == 0 && t < D_DIM) {
        float ks = 0.0f;
        const float* kb = ksp + (size_t)nh * NCHUNK * D_DIM + t;
        #pragma unroll
        for (int c = 0; c < NCHUNK; ++c) ks += kb[(size_t)c * D_DIM];
        Ksum[(size_t)nh * D_DIM + t] = ks;
    }
}

// ---------------- Phase 2: out = (Q·KV) / (Q·Ksum + eps) ----------------
// Grid remap: b = ((n*nblk + rb) * 8) + h  -> 8 consecutive blocks cover all
// heads of the same row range (contiguous Q reads / out writes).
__global__ __launch_bounds__(256) void out_kernel(
        const float* __restrict__ Qin, const float* __restrict__ KV,
        const float* __restrict__ Ksum, float* __restrict__ Out) {
    constexpr int RPB  = 128;
    constexpr int QPAD = 68;
    __shared__ __align__(16) float KVs[D_DIM][D_DIM];   // 16 KB
    __shared__ __align__(16) float Kss[D_DIM];
    __shared__ __align__(16) float Qs[RPB][QPAD];       // 34.8 KB, XOR-swizzled cols

    const int b    = blockIdx.x;
    const int nblk = S_LEN / RPB;          // 64
    const int h_i  = b & 7;
    const int rest = b >> 3;
    const int rb   = rest & (nblk - 1);
    const int n_i  = rest >> 6;            // nblk = 64
    const int nh   = n_i * H_N + h_i;
    const int t    = threadIdx.x;

    const float* Qb = Qin + (size_t)n_i * S_LEN * ROWSTRIDE + (size_t)h_i * D_DIM;
    float*       Ob = Out + (size_t)n_i * S_LEN * ROWSTRIDE + (size_t)h_i * D_DIM;

    {
        const float4* src = (const float4*)(KV + (size_t)nh * (D_DIM * D_DIM));
        float4* dst = (float4*)(&KVs[0][0]);
        #pragma unroll
        for (int i = 0; i < 4; ++i) dst[t + 256 * i] = src[t + 256 * i];
        if (t < 16) ((float4*)Kss)[t] = ((const float4*)(Ksum + (size_t)nh * D_DIM))[t];
    }

    const int ltx = t & 15, lty = t >> 4;
    const int sbase = rb * RPB;
    #pragma unroll
    for (int i = 0; i < 8; ++i) {
        const int row = lty + 16 * i;
        const float4 q = *(const float4*)(Qb + (size_t)(sbase + row) * ROWSTRIDE + ltx * 4);
        float4 f;
        f.x = felu1(q.x); f.y = felu1(q.y); f.z = felu1(q.z); f.w = felu1(q.w);
        const int pc = (ltx * 4) ^ (((row >> 2) & 7) << 2);
        *(float4*)&Qs[row][pc] = f;
    }
    __syncthreads();

    const int rg = t >> 3;                 // 0..31 -> rows rg*4..rg*4+3
    const int mg = t & 7;                  // 0..7  -> cols mg*8..mg*8+7
    const int r0 = rg * 4, m0 = mg * 8;
    const int sw = ((rg & 7) << 2);

    float acc[4][8];
    float zz[4];
    #pragma unroll
    for (int r = 0; r < 4; ++r) {
        zz[r] = 0.0f;
        #pragma unroll
        for (int m = 0; m < 8; ++m) acc[r][m] = 0.0f;
    }

    #pragma unroll
    for (int d0 = 0; d0 < D_DIM; d0 += 4) {
        const float4 ks4 = *(const float4*)&Kss[d0];
        float4 qr[4];
        #pragma unroll
        for (int r = 0; r < 4; ++r) {
            qr[r] = *(const float4*)&Qs[r0 + r][d0 ^ sw];
            zz[r] += qr[r].x * ks4.x + qr[r].y * ks4.y
                   + qr[r].z * ks4.z + qr[r].w * ks4.w;
        }
        #pragma unroll
        for (int j = 0; j < 4; ++j) {
            const float4 kva = *(const float4*)&KVs[d0 + j][m0];
            const float4 kvb = *(const float4*)&KVs[d0 + j][m0 + 4];
            #pragma unroll
            for (int r = 0; r < 4; ++r) {
                const float q = (&qr[r].x)[j];
                acc[r][0] += q * kva.x; acc[r][1] += q * kva.y;
                acc[r][2] += q * kva.z; acc[r][3] += q * kva.w;
                acc[r][4] += q * kvb.x; acc[r][5] += q * kvb.y;
                acc[r][6] += q * kvb.z; acc[r][7] += q * kvb.w;
            }
        }
    }

    #pragma unroll
    for (int r = 0; r < 4; ++r) {
        const float z = 1.0f / (zz[r] + EPS);
        float4 o1, o2;
        o1.x = acc[r][0] * z; o1.y = acc[r][1] * z;
        o1.z = acc[r][2] * z; o1.w = acc[r][3] * z;
        o2.x = acc[r][4] * z; o2.y = acc[r][5] * z;
        o2.z = acc[r][6] * z; o2.w = acc[r][7] * z;
        float* op = Ob + (size_t)(sbase + r0 + r) * ROWSTRIDE + m0;
        *(float4*)op       = o1;
        *(float4*)(op + 4) = o2;
    }
}

extern "C" void kernel_launch(void* const* d_in, const int* in_sizes, int n_in,
                              void* d_out, int out_size, void* d_ws, size_t ws_size,
                              hipStream_t stream) {
    const float* q = (const float*)d_in[0];
    const float* k = (const float*)d_in[1];
    const float* v = (const float*)d_in[2];
    float* out = (float*)d_out;

    float* kvp  = (float*)d_ws;
    float* ksp  = kvp + (size_t)NH * NCHUNK * D_DIM * D_DIM;
    float* KVf  = ksp + (size_t)NH * NCHUNK * D_DIM;
    float* Ksum = KVf + (size_t)NH * D_DIM * D_DIM;

    kv_partial_kernel<<<NH * NCHUNK, 256, 0, stream>>>(k, v, kvp, ksp);
    kv_reduce_kernel<<<NH * 16, 256, 0, stream>>>(kvp, ksp, KVf, Ksum);
    out_kernel<<<NH * (S_LEN / 128), 256, 0, stream>>>(q, KVf, Ksum, out);
}